// Round 1
// baseline (1483.866 us; speedup 1.0000x reference)
//
#include <hip/hip_runtime.h>
#include <hip/hip_bf16.h>

// DCSAGE_GRU: 2x (SAGE mean-aggr + GraphNorm + ReLU) -> GRU1 -> GRU2
// N=100000 nodes, E=1600000 edges, F=EMB=64. All f32.

#define WAVE 64

__device__ __forceinline__ float sigmoidf_(float x){ return 1.f/(1.f+__expf(-x)); }

// ---------------- CSR build ----------------
__global__ void k_count(const int* __restrict__ ei, int E, int* __restrict__ deg){
  int e = blockIdx.x*256 + threadIdx.x;
  if(e<E) atomicAdd(&deg[ei[E+e]], 1);
}

__global__ void k_scan(const int* __restrict__ deg, int N, int E,
                       int* __restrict__ rowptr, int* __restrict__ cursor){
  __shared__ int sh[1024];
  int t = threadIdx.x;
  int chunk = (N + 1023)/1024;
  int i0 = t*chunk, i1 = min(i0+chunk, N);
  int s = 0;
  for(int i=i0;i<i1;i++) s += deg[i];
  sh[t]=s; __syncthreads();
  for(int off=1; off<1024; off<<=1){
    int v = (t>=off)? sh[t-off] : 0;
    __syncthreads();
    sh[t] += v;
    __syncthreads();
  }
  int base = sh[t]-s; // exclusive prefix
  for(int i=i0;i<i1;i++){ rowptr[i]=base; cursor[i]=base; base += deg[i]; }
  if(t==1023) rowptr[N] = sh[1023];
}

__global__ void k_fill(const int* __restrict__ ei, const float* __restrict__ ea, int E,
                       int* __restrict__ cursor, int* __restrict__ srcs, float* __restrict__ ews){
  int e = blockIdx.x*256 + threadIdx.x;
  if(e<E){
    int d = ei[E+e];
    int p = atomicAdd(&cursor[d], 1);
    srcs[p] = ei[e];
    ews[p]  = ea[e];
  }
}

// ---------------- mean aggregation (one wave per node, lane = feature) ----------------
__global__ void k_aggregate(const float* __restrict__ xin, int ldx,
                            const int* __restrict__ rowptr,
                            const int* __restrict__ srcs, const float* __restrict__ ews,
                            int N, float* __restrict__ agg){
  int node = blockIdx.x*4 + (threadIdx.x>>6);
  int lane = threadIdx.x & 63;
  if(node>=N) return;
  int b = rowptr[node], e = rowptr[node+1];
  float acc = 0.f;
  for(int i=b;i<e;i++){
    int s   = srcs[i];
    float w = ews[i];
    acc = fmaf(xin[s*ldx + lane], w, acc);
  }
  float inv = 1.f / (float)max(e-b, 1);
  agg[node*64 + lane] = acc*inv;
}

// ---------------- SAGE gemm: s = agg@lW^T + x@rW^T + lb ; also per-feature sum/sumsq ----------------
__global__ __launch_bounds__(256) void k_sage_gemm(
    const float* __restrict__ agg,
    const float* __restrict__ xin, int ldx,
    const float* __restrict__ lW, const float* __restrict__ rW,
    const float* __restrict__ lb,
    int N, float* __restrict__ sbuf,
    float* __restrict__ gsum, float* __restrict__ gsq){
  __shared__ float As[32*132];   // [k][row], row-dim padded to 132
  __shared__ float Bs[32*68];    // [k][col], col-dim padded to 68
  int tid = threadIdx.x;
  int rowthr = tid>>4, colthr = tid&15;
  int bm0 = blockIdx.x*128;
  float acc[8][4];
  #pragma unroll
  for(int i=0;i<8;i++)
    #pragma unroll
    for(int j=0;j<4;j++) acc[i][j]=0.f;

  for(int kt=0;kt<4;kt++){
    const float* Asrc; int lda, koff;
    const float* Wsrc;
    if(kt<2){ Asrc=agg; lda=64;  koff=kt*32;     Wsrc=lW; }
    else    { Asrc=xin; lda=ldx; koff=(kt-2)*32; Wsrc=rW; }
    __syncthreads();
    #pragma unroll
    for(int i=0;i<16;i++){
      int idx = tid + i*256;
      int r = idx>>5, k = idx&31;
      int gr = bm0 + r;
      As[k*132 + r] = (gr<N) ? Asrc[gr*lda + koff + k] : 0.f;
    }
    #pragma unroll
    for(int i=0;i<8;i++){
      int idx = tid + i*256;
      int c = idx>>5, k = idx&31;
      Bs[k*68 + c] = Wsrc[c*64 + koff + k];
    }
    __syncthreads();
    #pragma unroll
    for(int kk=0;kk<32;kk++){
      float4 a0 = *reinterpret_cast<const float4*>(&As[kk*132 + rowthr*8]);
      float4 a1 = *reinterpret_cast<const float4*>(&As[kk*132 + rowthr*8 + 4]);
      float4 b  = *reinterpret_cast<const float4*>(&Bs[kk*68  + colthr*4]);
      float av[8] = {a0.x,a0.y,a0.z,a0.w,a1.x,a1.y,a1.z,a1.w};
      float bv[4] = {b.x,b.y,b.z,b.w};
      #pragma unroll
      for(int i=0;i<8;i++)
        #pragma unroll
        for(int j=0;j<4;j++)
          acc[i][j] = fmaf(av[i], bv[j], acc[i][j]);
    }
  }

  float bias[4];
  #pragma unroll
  for(int j=0;j<4;j++) bias[j] = lb[colthr*4+j];
  float ssum[4]={0,0,0,0}, ssq[4]={0,0,0,0};
  #pragma unroll
  for(int i=0;i<8;i++){
    int gr = bm0 + rowthr*8 + i;
    if(gr<N){
      float4 s4;
      float sv[4];
      #pragma unroll
      for(int j=0;j<4;j++){
        float s = acc[i][j] + bias[j];
        sv[j]=s; ssum[j]+=s; ssq[j]+=s*s;
      }
      s4.x=sv[0]; s4.y=sv[1]; s4.z=sv[2]; s4.w=sv[3];
      *reinterpret_cast<float4*>(&sbuf[gr*64 + colthr*4]) = s4;
    }
  }
  // deterministic per-block reduce of stats, then 128 global atomics
  __syncthreads();
  float* p1 = As;          // [16][64]
  float* p2 = As + 1024;   // [16][64]
  #pragma unroll
  for(int j=0;j<4;j++){
    p1[rowthr*64 + colthr*4 + j] = ssum[j];
    p2[rowthr*64 + colthr*4 + j] = ssq[j];
  }
  __syncthreads();
  if(tid<64){
    float a=0.f, b2=0.f;
    #pragma unroll
    for(int r=0;r<16;r++){ a += p1[r*64+tid]; b2 += p2[r*64+tid]; }
    atomicAdd(&gsum[tid], a);
    atomicAdd(&gsq[tid],  b2);
  }
}

// ---------------- GraphNorm finalize: per-feature alpha/beta ----------------
__global__ void k_norm_fin(const float* __restrict__ gsum, const float* __restrict__ gsq,
                           const float* __restrict__ w, const float* __restrict__ b,
                           const float* __restrict__ ms,
                           float Ninv, float* __restrict__ alpha, float* __restrict__ beta){
  int j = threadIdx.x;
  float m   = gsum[j]*Ninv;
  float ex2 = gsq[j]*Ninv;
  float msv = ms[j];
  float var = ex2 - m*m*msv*(2.f-msv);   // E[(s-ms*m)^2]
  float rinv = rsqrtf(var + 1e-5f);
  float a = w[j]*rinv;
  alpha[j] = a;
  beta[j]  = b[j] - a*msv*m;
}

// ---------------- y = relu(alpha*s + beta) -> d_out xc slab (row stride 128) ----------------
__global__ void k_apply(const float* __restrict__ sbuf, const float* __restrict__ ab,
                        int N, float* __restrict__ outbase){
  int t = blockIdx.x*256 + threadIdx.x;
  int total = N*16;
  if(t>=total) return;
  int node = t>>4, q = t&15;
  float4 s  = *reinterpret_cast<const float4*>(&sbuf[node*64 + q*4]);
  float4 al = *reinterpret_cast<const float4*>(&ab[q*4]);
  float4 be = *reinterpret_cast<const float4*>(&ab[64 + q*4]);
  float4 o;
  o.x = fmaxf(fmaf(s.x,al.x,be.x), 0.f);
  o.y = fmaxf(fmaf(s.y,al.y,be.y), 0.f);
  o.z = fmaxf(fmaf(s.z,al.z,be.z), 0.f);
  o.w = fmaxf(fmaf(s.w,al.w,be.w), 0.f);
  *reinterpret_cast<float4*>(&outbase[node*128 + q*4]) = o;
}

// ---------------- fused GRU: gi (K1) + gh (64) + gates, writes h' ----------------
__global__ __launch_bounds__(256) void k_gru(
    const float* __restrict__ xin, int ldx, int K1,
    const float* __restrict__ hin,
    const float* __restrict__ wih,   // [192][K1]
    const float* __restrict__ whh,   // [192][64]
    const float* __restrict__ bih, const float* __restrict__ bhh,
    int N, float* __restrict__ hout){
  __shared__ float As[32*68];     // [k][row] 64 rows pad 68
  __shared__ float Ws[32*196];    // [k][col] 192 cols pad 196
  int tid = threadIdx.x;
  int rowthr = tid>>4, colthr = tid&15;
  int bm0 = blockIdx.x*64;
  float acc_i[4][12], acc_h[4][12];
  #pragma unroll
  for(int i=0;i<4;i++)
    #pragma unroll
    for(int j=0;j<12;j++){ acc_i[i][j]=0.f; acc_h[i][j]=0.f; }

  // phase 1: acc_i = xin @ wih^T  (K1 = 128 or 64)
  for(int kt=0; kt<K1/32; kt++){
    int koff = kt*32;
    __syncthreads();
    #pragma unroll
    for(int i=0;i<8;i++){
      int idx = tid + i*256;
      int r = idx>>5, k = idx&31;
      int gr = bm0 + r;
      As[k*68 + r] = (gr<N) ? xin[gr*ldx + koff + k] : 0.f;
    }
    #pragma unroll
    for(int i=0;i<24;i++){
      int idx = tid + i*256;
      int c = idx>>5, k = idx&31;
      Ws[k*196 + c] = wih[c*K1 + koff + k];
    }
    __syncthreads();
    #pragma unroll
    for(int kk=0;kk<32;kk++){
      float4 a = *reinterpret_cast<const float4*>(&As[kk*68 + rowthr*4]);
      float av[4] = {a.x,a.y,a.z,a.w};
      #pragma unroll
      for(int g=0; g<3; g++){
        float4 b = *reinterpret_cast<const float4*>(&Ws[kk*196 + g*64 + colthr*4]);
        float bv[4] = {b.x,b.y,b.z,b.w};
        #pragma unroll
        for(int i=0;i<4;i++)
          #pragma unroll
          for(int q=0;q<4;q++)
            acc_i[i][g*4+q] = fmaf(av[i], bv[q], acc_i[i][g*4+q]);
      }
    }
  }
  // phase 2: acc_h = hin @ whh^T (K=64)
  for(int kt=0; kt<2; kt++){
    int koff = kt*32;
    __syncthreads();
    #pragma unroll
    for(int i=0;i<8;i++){
      int idx = tid + i*256;
      int r = idx>>5, k = idx&31;
      int gr = bm0 + r;
      As[k*68 + r] = (gr<N) ? hin[gr*64 + koff + k] : 0.f;
    }
    #pragma unroll
    for(int i=0;i<24;i++){
      int idx = tid + i*256;
      int c = idx>>5, k = idx&31;
      Ws[k*196 + c] = whh[c*64 + koff + k];
    }
    __syncthreads();
    #pragma unroll
    for(int kk=0;kk<32;kk++){
      float4 a = *reinterpret_cast<const float4*>(&As[kk*68 + rowthr*4]);
      float av[4] = {a.x,a.y,a.z,a.w};
      #pragma unroll
      for(int g=0; g<3; g++){
        float4 b = *reinterpret_cast<const float4*>(&Ws[kk*196 + g*64 + colthr*4]);
        float bv[4] = {b.x,b.y,b.z,b.w};
        #pragma unroll
        for(int i=0;i<4;i++)
          #pragma unroll
          for(int q=0;q<4;q++)
            acc_h[i][g*4+q] = fmaf(av[i], bv[q], acc_h[i][g*4+q]);
      }
    }
  }
  // gates
  int jj = colthr*4;
  float bihv[12], bhhv[12];
  #pragma unroll
  for(int g=0;g<3;g++)
    #pragma unroll
    for(int q=0;q<4;q++){
      bihv[g*4+q] = bih[g*64 + jj + q];
      bhhv[g*4+q] = bhh[g*64 + jj + q];
    }
  #pragma unroll
  for(int i=0;i<4;i++){
    int gr = bm0 + rowthr*4 + i;
    if(gr<N){
      float4 hp4 = *reinterpret_cast<const float4*>(&hin[gr*64 + jj]);
      float hp[4] = {hp4.x,hp4.y,hp4.z,hp4.w};
      float ov[4];
      #pragma unroll
      for(int q=0;q<4;q++){
        float ir  = acc_i[i][q]   + bihv[q];
        float iz  = acc_i[i][4+q] + bihv[4+q];
        float in_ = acc_i[i][8+q] + bihv[8+q];
        float hr  = acc_h[i][q]   + bhhv[q];
        float hz  = acc_h[i][4+q] + bhhv[4+q];
        float hn  = acc_h[i][8+q] + bhhv[8+q];
        float r = sigmoidf_(ir+hr);
        float z = sigmoidf_(iz+hz);
        float n = tanhf(fmaf(r, hn, in_));
        ov[q] = fmaf(z, hp[q]-n, n);   // (1-z)*n + z*h
      }
      float4 o4; o4.x=ov[0]; o4.y=ov[1]; o4.z=ov[2]; o4.w=ov[3];
      *reinterpret_cast<float4*>(&hout[gr*64 + jj]) = o4;
    }
  }
}

extern "C" void kernel_launch(void* const* d_in, const int* in_sizes, int n_in,
                              void* d_out, int out_size, void* d_ws, size_t ws_size,
                              hipStream_t stream) {
  const float* x    = (const float*)d_in[0];
  const int*   ei   = (const int*)d_in[1];
  const float* ea   = (const float*)d_in[2];
  const float* h1   = (const float*)d_in[3];
  const float* h2   = (const float*)d_in[4];
  const float* s1lW = (const float*)d_in[5];
  const float* s1lb = (const float*)d_in[6];
  const float* s1rW = (const float*)d_in[7];
  const float* s2lW = (const float*)d_in[8];
  const float* s2lb = (const float*)d_in[9];
  const float* s2rW = (const float*)d_in[10];
  const float* gn1w = (const float*)d_in[11];
  const float* gn1b = (const float*)d_in[12];
  const float* gn1ms= (const float*)d_in[13];
  const float* gn2w = (const float*)d_in[14];
  const float* gn2b = (const float*)d_in[15];
  const float* gn2ms= (const float*)d_in[16];
  const float* g1wih= (const float*)d_in[17];
  const float* g1whh= (const float*)d_in[18];
  const float* g1bih= (const float*)d_in[19];
  const float* g1bhh= (const float*)d_in[20];
  const float* g2wih= (const float*)d_in[21];
  const float* g2whh= (const float*)d_in[22];
  const float* g2bih= (const float*)d_in[23];
  const float* g2bhh= (const float*)d_in[24];

  int N = in_sizes[0]/64;
  int E = in_sizes[2];
  if(N<=0) return;

  // workspace layout (floats/ints): stats(256) | ab1(128) | ab2(128) | deg N | rowptr N+64 | cursor N | srcs E | ews E
  float* ws    = (float*)d_ws;
  float* gsum1 = ws;          float* gsq1 = ws+64;
  float* gsum2 = ws+128;      float* gsq2 = ws+192;
  float* ab1   = ws+256;
  float* ab2   = ws+384;
  int*   deg    = (int*)(ws+512);
  int*   rowptr = deg + N;
  int*   cursor = rowptr + N + 64;
  int*   srcs   = cursor + N;
  float* ews    = (float*)(srcs + E);

  float* xc  = (float*)d_out;                 // [N][128]
  float* h1n = xc + (size_t)N*128;            // [N][64]
  float* h2n = h1n + (size_t)N*64;            // [N][64]
  // reuse d_out tail (h1n/h2n not yet written) as SAGE scratch
  float* sbuf = h1n;                           // [N][64] raw sage output
  float* agg  = h2n;                           // [N][64] mean aggregate

  hipMemsetAsync(ws, 0, 512*4, stream);
  hipMemsetAsync(deg, 0, (size_t)N*4, stream);

  int eb = (E+255)/256;
  k_count<<<eb,256,0,stream>>>(ei, E, deg);
  k_scan <<<1,1024,0,stream>>>(deg, N, E, rowptr, cursor);
  k_fill <<<eb,256,0,stream>>>(ei, ea, E, cursor, srcs, ews);

  int nb4 = (N+3)/4;
  int gb  = (N+127)/128;
  int apb = (N*16+255)/256;
  int grb = (N+63)/64;

  // layer 1
  k_aggregate<<<nb4,256,0,stream>>>(x, 64, rowptr, srcs, ews, N, agg);
  k_sage_gemm<<<gb,256,0,stream>>>(agg, x, 64, s1lW, s1rW, s1lb, N, sbuf, gsum1, gsq1);
  k_norm_fin<<<1,64,0,stream>>>(gsum1, gsq1, gn1w, gn1b, gn1ms, 1.f/(float)N, ab1, ab1+64);
  k_apply<<<apb,256,0,stream>>>(sbuf, ab1, N, xc);          // x1 -> cols 0..63

  // layer 2 (reads x1 from d_out, stride 128)
  k_aggregate<<<nb4,256,0,stream>>>(xc, 128, rowptr, srcs, ews, N, agg);
  k_sage_gemm<<<gb,256,0,stream>>>(agg, xc, 128, s2lW, s2rW, s2lb, N, sbuf, gsum2, gsq2);
  k_norm_fin<<<1,64,0,stream>>>(gsum2, gsq2, gn2w, gn2b, gn2ms, 1.f/(float)N, ab2, ab2+64);
  k_apply<<<apb,256,0,stream>>>(sbuf, ab2, N, xc + 64);     // x2 -> cols 64..127

  // GRUs (fused gi+gh+gates) — overwrite the scratch regions with real h1n/h2n
  k_gru<<<grb,256,0,stream>>>(xc, 128, 128, h1, g1wih, g1whh, g1bih, g1bhh, N, h1n);
  k_gru<<<grb,256,0,stream>>>(h1n, 64, 64,  h2, g2wih, g2whh, g2bih, g2bhh, N, h2n);
}

// Round 4
// 994.863 us; speedup vs baseline: 1.4915x; 1.4915x over previous
//
#include <hip/hip_runtime.h>
#include <hip/hip_bf16.h>

// DCSAGE_GRU: 2x (SAGE mean-aggr + GraphNorm + ReLU) -> GRU1 -> GRU2
// N=100000 nodes, E=1600000 edges, F=EMB=64. f32 I/O, bf16 MFMA GEMMs.

typedef short  s16x8 __attribute__((ext_vector_type(8)));
typedef float  f32x4 __attribute__((ext_vector_type(4)));

#define MFMA16(a,b,c) __builtin_amdgcn_mfma_f32_16x16x32_bf16((a),(b),(c),0,0,0)

__device__ __forceinline__ unsigned short f2b(float f){
  __hip_bfloat16 h = __float2bfloat16(f);
  return *reinterpret_cast<unsigned short*>(&h);
}
__device__ __forceinline__ float b2f(unsigned short u){
  __hip_bfloat16 h = *reinterpret_cast<__hip_bfloat16*>(&u);
  return __bfloat162float(h);
}
__device__ __forceinline__ s16x8 ld8(const unsigned short* p){
  return *reinterpret_cast<const s16x8*>(p);
}
// load 8 consecutive f32, convert to bf16 frag (compiler emits v_cvt pairs)
__device__ __forceinline__ s16x8 cvt8(const float* p){
  float4 a = *reinterpret_cast<const float4*>(p);
  float4 b = *reinterpret_cast<const float4*>(p+4);
  s16x8 r;
  r[0]=(short)f2b(a.x); r[1]=(short)f2b(a.y); r[2]=(short)f2b(a.z); r[3]=(short)f2b(a.w);
  r[4]=(short)f2b(b.x); r[5]=(short)f2b(b.y); r[6]=(short)f2b(b.z); r[7]=(short)f2b(b.w);
  return r;
}
__device__ __forceinline__ float sigf(float x){ return 1.f/(1.f+__expf(-x)); }
__device__ __forceinline__ float tanhf_(float x){ return 1.f - 2.f/(1.f+__expf(2.f*x)); }

// ---------------- CSR build ----------------
__global__ void k_count(const int* __restrict__ ei, int E, int* __restrict__ deg){
  int e = blockIdx.x*256 + threadIdx.x;
  if(e<E) atomicAdd(&deg[ei[E+e]], 1);
}

__global__ void k_scan(const int* __restrict__ deg, int N, int E,
                       int* __restrict__ rowptr, int* __restrict__ cursor){
  __shared__ int sh[1024];
  int t = threadIdx.x;
  int chunk = (N + 1023)/1024;
  int i0 = t*chunk, i1 = min(i0+chunk, N);
  int s = 0;
  for(int i=i0;i<i1;i++) s += deg[i];
  sh[t]=s; __syncthreads();
  for(int off=1; off<1024; off<<=1){
    int v = (t>=off)? sh[t-off] : 0;
    __syncthreads();
    sh[t] += v;
    __syncthreads();
  }
  int base = sh[t]-s; // exclusive prefix
  for(int i=i0;i<i1;i++){ rowptr[i]=base; cursor[i]=base; base += deg[i]; }
  if(t==1023) rowptr[N] = sh[1023];
}

__global__ void k_fill(const int* __restrict__ ei, const float* __restrict__ ea, int E,
                       int* __restrict__ cursor, int* __restrict__ srcs,
                       unsigned short* __restrict__ ewb){
  int e = blockIdx.x*256 + threadIdx.x;
  if(e<E){
    int d = ei[E+e];
    int p = atomicAdd(&cursor[d], 1);
    srcs[p] = ei[e];
    ewb[p]  = f2b(ea[e]);
  }
}

// ---------------- weight f32 -> bf16 prep (8 arrays packed into wbf) ----------------
__global__ void k_prep_w(const float* __restrict__ a0, const float* __restrict__ a1,
                         const float* __restrict__ a2, const float* __restrict__ a3,
                         const float* __restrict__ a4, const float* __restrict__ a5,
                         const float* __restrict__ a6, const float* __restrict__ a7,
                         unsigned short* __restrict__ out){
  int i = blockIdx.x*256 + threadIdx.x;
  const float* src; int off;
  if      (i< 4096){ src=a0; off=0;     }
  else if (i< 8192){ src=a1; off=4096;  }
  else if (i<12288){ src=a2; off=8192;  }
  else if (i<16384){ src=a3; off=12288; }
  else if (i<40960){ src=a4; off=16384; }
  else if (i<53248){ src=a5; off=40960; }
  else if (i<65536){ src=a6; off=53248; }
  else if (i<77824){ src=a7; off=65536; }
  else return;
  out[i] = f2b(src[i-off]);
}

// ---------------- mean aggregation (wave per node, lane = feature, 4-deep gather) ----------------
__global__ void k_aggregate(const float* __restrict__ xin, int ldx,
                            const int* __restrict__ rowptr,
                            const int* __restrict__ srcs, const unsigned short* __restrict__ ewb,
                            int N, unsigned short* __restrict__ aggb){
  int node = blockIdx.x*4 + (threadIdx.x>>6);
  int lane = threadIdx.x & 63;
  if(node>=N) return;
  int b = rowptr[node], e = rowptr[node+1];
  float acc = 0.f;
  int i = b;
  for(; i+4<=e; i+=4){
    int s0=srcs[i], s1=srcs[i+1], s2=srcs[i+2], s3=srcs[i+3];
    float w0=b2f(ewb[i]),  w1=b2f(ewb[i+1]), w2=b2f(ewb[i+2]), w3=b2f(ewb[i+3]);
    float v0=xin[(size_t)s0*ldx+lane], v1=xin[(size_t)s1*ldx+lane];
    float v2=xin[(size_t)s2*ldx+lane], v3=xin[(size_t)s3*ldx+lane];
    acc = fmaf(v0,w0,acc); acc = fmaf(v1,w1,acc);
    acc = fmaf(v2,w2,acc); acc = fmaf(v3,w3,acc);
  }
  for(; i<e; i++)
    acc = fmaf(xin[(size_t)srcs[i]*ldx+lane], b2f(ewb[i]), acc);
  acc *= 1.f/(float)max(e-b, 1);
  aggb[(size_t)node*64 + lane] = f2b(acc);
}

// ---------------- SAGE MFMA: s = agg@lW^T + x@rW^T + lb ; per-feature stats ----------------
// block = 256 thr = 4 waves, wave = 16 rows x 64 cols, no LDS for GEMM.
__global__ __launch_bounds__(256) void k_sage_mfma(
    const unsigned short* __restrict__ aggb,   // [N][64] bf16
    const float* __restrict__ xin, int ldx,    // [N][ldx] f32, cols 0..63
    const unsigned short* __restrict__ lWb,    // [64][64] bf16 (torch [out][in])
    const unsigned short* __restrict__ rWb,    // [64][64] bf16
    const float* __restrict__ lb,
    int N, float* __restrict__ sbuf,
    float* __restrict__ gsum, float* __restrict__ gsq){
  __shared__ float red[2][4][64];
  int tid = threadIdx.x;
  int wid = tid>>6, lane = tid&63;
  int l15 = lane&15, lk = lane>>4;
  int m0 = blockIdx.x*64 + wid*16;
  int arow = min(m0 + l15, N-1);
  f32x4 acc[4];
  #pragma unroll
  for(int c=0;c<4;c++) acc[c] = (f32x4){0.f,0.f,0.f,0.f};

  #pragma unroll
  for(int kt=0; kt<2; kt++){                    // agg @ lW^T (K=64)
    s16x8 a = ld8(&aggb[(size_t)arow*64 + kt*32 + lk*8]);
    #pragma unroll
    for(int c=0;c<4;c++){
      s16x8 b = ld8(&lWb[(size_t)(c*16+l15)*64 + kt*32 + lk*8]);
      acc[c] = MFMA16(a,b,acc[c]);
    }
  }
  #pragma unroll
  for(int kt=0; kt<2; kt++){                    // x @ rW^T (K=64)
    s16x8 a = cvt8(&xin[(size_t)arow*ldx + kt*32 + lk*8]);
    #pragma unroll
    for(int c=0;c<4;c++){
      s16x8 b = ld8(&rWb[(size_t)(c*16+l15)*64 + kt*32 + lk*8]);
      acc[c] = MFMA16(a,b,acc[c]);
    }
  }
  // epilogue: bias, store s, per-feature sum/sumsq
  float ssum[4], ssq[4];
  #pragma unroll
  for(int c=0;c<4;c++){
    int col = c*16 + l15;
    float bias = lb[col];
    float s_=0.f, q_=0.f;
    #pragma unroll
    for(int r=0;r<4;r++){
      int row = m0 + lk*4 + r;
      if(row<N){
        float v = acc[c][r] + bias;
        sbuf[(size_t)row*64 + col] = v;
        s_ += v; q_ += v*v;
      }
    }
    ssum[c]=s_; ssq[c]=q_;
  }
  #pragma unroll
  for(int c=0;c<4;c++){
    ssum[c] += __shfl_xor(ssum[c],16); ssum[c] += __shfl_xor(ssum[c],32);
    ssq[c]  += __shfl_xor(ssq[c],16);  ssq[c]  += __shfl_xor(ssq[c],32);
  }
  if(lk==0){
    #pragma unroll
    for(int c=0;c<4;c++){
      red[0][wid][c*16+l15] = ssum[c];
      red[1][wid][c*16+l15] = ssq[c];
    }
  }
  __syncthreads();
  if(tid<64){
    float a = red[0][0][tid]+red[0][1][tid]+red[0][2][tid]+red[0][3][tid];
    float b = red[1][0][tid]+red[1][1][tid]+red[1][2][tid]+red[1][3][tid];
    atomicAdd(&gsum[tid], a);
    atomicAdd(&gsq[tid],  b);
  }
}

// ---------------- GraphNorm finalize ----------------
__global__ void k_norm_fin(const float* __restrict__ gsum, const float* __restrict__ gsq,
                           const float* __restrict__ w, const float* __restrict__ b,
                           const float* __restrict__ ms,
                           float Ninv, float* __restrict__ alpha, float* __restrict__ beta){
  int j = threadIdx.x;
  float m   = gsum[j]*Ninv;
  float ex2 = gsq[j]*Ninv;
  float msv = ms[j];
  float var = ex2 - m*m*msv*(2.f-msv);   // E[(s-ms*m)^2]
  float rinv = rsqrtf(var + 1e-5f);
  float a = w[j]*rinv;
  alpha[j] = a;
  beta[j]  = b[j] - a*msv*m;
}

// ---------------- y = relu(alpha*s + beta) -> xc slab (row stride 128) ----------------
__global__ void k_apply(const float* __restrict__ sbuf, const float* __restrict__ ab,
                        int N, float* __restrict__ outbase){
  int t = blockIdx.x*256 + threadIdx.x;
  int total = N*16;
  if(t>=total) return;
  int node = t>>4, q = t&15;
  float4 s  = *reinterpret_cast<const float4*>(&sbuf[(size_t)node*64 + q*4]);
  float4 al = *reinterpret_cast<const float4*>(&ab[q*4]);
  float4 be = *reinterpret_cast<const float4*>(&ab[64 + q*4]);
  float4 o;
  o.x = fmaxf(fmaf(s.x,al.x,be.x), 0.f);
  o.y = fmaxf(fmaf(s.y,al.y,be.y), 0.f);
  o.z = fmaxf(fmaf(s.z,al.z,be.z), 0.f);
  o.w = fmaxf(fmaf(s.w,al.w,be.w), 0.f);
  *reinterpret_cast<float4*>(&outbase[(size_t)node*128 + q*4]) = o;
}

// ---------------- fused GRU via MFMA ----------------
// block = 256 thr = 4 waves; block covers 16 rows; wave w = gate-col tile c0=w*16.
// acc_i[g], acc_h[g] for g in {r,z,n}: 6 frags = 24 f32/lane. No LDS, no barriers.
__global__ __launch_bounds__(256) void k_gru_mfma(
    const float* __restrict__ xin, int ldx, int K1, // gi input [N][ldx] f32
    const float* __restrict__ hin,                  // [N][64] f32 (gh input + h_prev)
    const unsigned short* __restrict__ wihb,        // [192][K1] bf16
    const unsigned short* __restrict__ whhb,        // [192][64] bf16
    const float* __restrict__ bih, const float* __restrict__ bhh,
    int N, float* __restrict__ hout){
  int tid = threadIdx.x;
  int wid = tid>>6, lane = tid&63;
  int l15 = lane&15, lk = lane>>4;
  int m0 = blockIdx.x*16;
  int c0 = wid*16;
  int arow = min(m0 + l15, N-1);
  f32x4 ai[3], ah[3];
  #pragma unroll
  for(int g=0;g<3;g++){ ai[g]=(f32x4){0.f,0.f,0.f,0.f}; ah[g]=(f32x4){0.f,0.f,0.f,0.f}; }

  for(int kt=0; kt<K1/32; kt++){                // gi: xin @ wih^T
    s16x8 a = cvt8(&xin[(size_t)arow*ldx + kt*32 + lk*8]);
    #pragma unroll
    for(int g=0; g<3; g++){
      s16x8 b = ld8(&wihb[(size_t)(g*64 + c0 + l15)*K1 + kt*32 + lk*8]);
      ai[g] = MFMA16(a,b,ai[g]);
    }
  }
  #pragma unroll
  for(int kt=0; kt<2; kt++){                    // gh: hin @ whh^T (K=64)
    s16x8 a = cvt8(&hin[(size_t)arow*64 + kt*32 + lk*8]);
    #pragma unroll
    for(int g=0; g<3; g++){
      s16x8 b = ld8(&whhb[(size_t)(g*64 + c0 + l15)*64 + kt*32 + lk*8]);
      ah[g] = MFMA16(a,b,ah[g]);
    }
  }
  int j = c0 + l15;
  float bi_r=bih[j], bi_z=bih[64+j], bi_n=bih[128+j];
  float bh_r=bhh[j], bh_z=bhh[64+j], bh_n=bhh[128+j];
  #pragma unroll
  for(int r=0;r<4;r++){
    int row = m0 + lk*4 + r;
    if(row<N){
      float hp = hin[(size_t)row*64 + j];
      float rg = sigf(ai[0][r]+bi_r + ah[0][r]+bh_r);
      float z  = sigf(ai[1][r]+bi_z + ah[1][r]+bh_z);
      float n  = tanhf_(fmaf(rg, ah[2][r]+bh_n, ai[2][r]+bi_n));
      hout[(size_t)row*64 + j] = fmaf(z, hp-n, n);
    }
  }
}

extern "C" void kernel_launch(void* const* d_in, const int* in_sizes, int n_in,
                              void* d_out, int out_size, void* d_ws, size_t ws_size,
                              hipStream_t stream) {
  const float* x    = (const float*)d_in[0];
  const int*   ei   = (const int*)d_in[1];
  const float* ea   = (const float*)d_in[2];
  const float* h1   = (const float*)d_in[3];
  const float* h2   = (const float*)d_in[4];
  const float* s1lW = (const float*)d_in[5];
  const float* s1lb = (const float*)d_in[6];
  const float* s1rW = (const float*)d_in[7];
  const float* s2lW = (const float*)d_in[8];
  const float* s2lb = (const float*)d_in[9];
  const float* s2rW = (const float*)d_in[10];
  const float* gn1w = (const float*)d_in[11];
  const float* gn1b = (const float*)d_in[12];
  const float* gn1ms= (const float*)d_in[13];
  const float* gn2w = (const float*)d_in[14];
  const float* gn2b = (const float*)d_in[15];
  const float* gn2ms= (const float*)d_in[16];
  const float* g1wih= (const float*)d_in[17];
  const float* g1whh= (const float*)d_in[18];
  const float* g1bih= (const float*)d_in[19];
  const float* g1bhh= (const float*)d_in[20];
  const float* g2wih= (const float*)d_in[21];
  const float* g2whh= (const float*)d_in[22];
  const float* g2bih= (const float*)d_in[23];
  const float* g2bhh= (const float*)d_in[24];

  int N = in_sizes[0]/64;
  int E = in_sizes[2];
  if(N<=0) return;

  // ---- workspace layout (bytes) ----
  char* base = (char*)d_ws;
  size_t off = 0;
  float* gsum1 = (float*)(base);      // 512 f32: stats + ab
  float* gsq1  = gsum1 + 64;
  float* gsum2 = gsum1 + 128;
  float* gsq2  = gsum1 + 192;
  float* ab1   = gsum1 + 256;
  float* ab2   = gsum1 + 384;
  off = 512*4;
  int* deg    = (int*)(base+off); off += (size_t)N*4;
  int* rowptr = (int*)(base+off); off += ((size_t)N+1)*4;
  int* cursor = (int*)(base+off); off += (size_t)N*4;
  int* srcs   = (int*)(base+off); off += (size_t)E*4;
  unsigned short* ewb = (unsigned short*)(base+off); off += (size_t)E*2;
  off = (off + 63) & ~(size_t)63;
  unsigned short* wbf = (unsigned short*)(base+off);
  unsigned short* s1lWb = wbf;
  unsigned short* s1rWb = wbf + 4096;
  unsigned short* s2lWb = wbf + 8192;
  unsigned short* s2rWb = wbf + 12288;
  unsigned short* g1wihb= wbf + 16384;   // 24576
  unsigned short* g1whhb= wbf + 40960;   // 12288
  unsigned short* g2wihb= wbf + 53248;   // 12288
  unsigned short* g2whhb= wbf + 65536;   // 12288  (total 77824)

  // ---- d_out regions ----
  float* xc  = (float*)d_out;                  // [N][128]
  float* h1n = xc + (size_t)N*128;             // [N][64]
  float* h2n = h1n + (size_t)N*64;             // [N][64]
  float* sbuf = h1n;                           // raw SAGE out, dead before GRU1 writes h1n
  unsigned short* aggb = (unsigned short*)h2n; // [N][64] bf16, dead before GRU2 writes h2n

  hipMemsetAsync(gsum1, 0, 512*4, stream);
  hipMemsetAsync(deg, 0, (size_t)N*4, stream);

  int eb  = (E+255)/256;
  k_count<<<eb,256,0,stream>>>(ei, E, deg);
  k_scan <<<1,1024,0,stream>>>(deg, N, E, rowptr, cursor);
  k_fill <<<eb,256,0,stream>>>(ei, ea, E, cursor, srcs, ewb);
  k_prep_w<<<(77824+255)/256,256,0,stream>>>(s1lW,s1rW,s2lW,s2rW,g1wih,g1whh,g2wih,g2whh, wbf);

  int nb4 = (N+3)/4;
  int gb  = (N+63)/64;
  int apb = (N*16+255)/256;
  int grb = (N+15)/16;

  // layer 1
  k_aggregate<<<nb4,256,0,stream>>>(x, 64, rowptr, srcs, ewb, N, aggb);
  k_sage_mfma<<<gb,256,0,stream>>>(aggb, x, 64, s1lWb, s1rWb, s1lb, N, sbuf, gsum1, gsq1);
  k_norm_fin<<<1,64,0,stream>>>(gsum1, gsq1, gn1w, gn1b, gn1ms, 1.f/(float)N, ab1, ab1+64);
  k_apply<<<apb,256,0,stream>>>(sbuf, ab1, N, xc);          // x1 -> cols 0..63

  // layer 2 (x1 read from xc, stride 128)
  k_aggregate<<<nb4,256,0,stream>>>(xc, 128, rowptr, srcs, ewb, N, aggb);
  k_sage_mfma<<<gb,256,0,stream>>>(aggb, xc, 128, s2lWb, s2rWb, s2lb, N, sbuf, gsum2, gsq2);
  k_norm_fin<<<1,64,0,stream>>>(gsum2, gsq2, gn2w, gn2b, gn2ms, 1.f/(float)N, ab2, ab2+64);
  k_apply<<<apb,256,0,stream>>>(sbuf, ab2, N, xc + 64);     // x2 -> cols 64..127

  // GRUs (MFMA, fused gates) — overwrite scratch regions with real h1n/h2n
  k_gru_mfma<<<grb,256,0,stream>>>(xc, 128, 128, h1, g1wihb, g1whhb, g1bih, g1bhh, N, h1n);
  k_gru_mfma<<<grb,256,0,stream>>>(h1n, 64, 64,  h2, g2wihb, g2whhb, g2bih, g2bhh, N, h2n);
}

// Round 5
// 784.639 us; speedup vs baseline: 1.8911x; 1.2679x over previous
//
#include <hip/hip_runtime.h>
#include <hip/hip_bf16.h>

// DCSAGE_GRU: 2x (SAGE mean-aggr + GraphNorm + ReLU) -> GRU1 -> GRU2
// N=100000 nodes, E=1600000 edges, F=EMB=64. f32 I/O, bf16 MFMA GEMMs.
// R5: parallel 3-phase CSR scan (was: 1-block k_scan @ 229us, 0.15% occupancy).

typedef short  s16x8 __attribute__((ext_vector_type(8)));
typedef float  f32x4 __attribute__((ext_vector_type(4)));

#define MFMA16(a,b,c) __builtin_amdgcn_mfma_f32_16x16x32_bf16((a),(b),(c),0,0,0)
#define SCAN_TILE 4096   // 256 threads x 16 elems

__device__ __forceinline__ unsigned short f2b(float f){
  __hip_bfloat16 h = __float2bfloat16(f);
  return *reinterpret_cast<unsigned short*>(&h);
}
__device__ __forceinline__ float b2f(unsigned short u){
  __hip_bfloat16 h = *reinterpret_cast<__hip_bfloat16*>(&u);
  return __bfloat162float(h);
}
__device__ __forceinline__ s16x8 ld8(const unsigned short* p){
  return *reinterpret_cast<const s16x8*>(p);
}
// load 8 consecutive f32, convert to bf16 frag
__device__ __forceinline__ s16x8 cvt8(const float* p){
  float4 a = *reinterpret_cast<const float4*>(p);
  float4 b = *reinterpret_cast<const float4*>(p+4);
  s16x8 r;
  r[0]=(short)f2b(a.x); r[1]=(short)f2b(a.y); r[2]=(short)f2b(a.z); r[3]=(short)f2b(a.w);
  r[4]=(short)f2b(b.x); r[5]=(short)f2b(b.y); r[6]=(short)f2b(b.z); r[7]=(short)f2b(b.w);
  return r;
}
__device__ __forceinline__ float sigf(float x){ return 1.f/(1.f+__expf(-x)); }
__device__ __forceinline__ float tanhf_(float x){ return 1.f - 2.f/(1.f+__expf(2.f*x)); }

// ---------------- CSR build ----------------
__global__ void k_count(const int* __restrict__ ei, int E, int* __restrict__ deg){
  int e = blockIdx.x*256 + threadIdx.x;
  if(e<E) atomicAdd(&deg[ei[E+e]], 1);
}

// phase 1: per-block tile sums
__global__ __launch_bounds__(256) void k_scan1(const int* __restrict__ deg, int N,
                                               int* __restrict__ bsum){
  __shared__ int sh[256];
  int b = blockIdx.x, t = threadIdx.x;
  int i0 = b*SCAN_TILE + t*16;
  int s = 0;
  #pragma unroll
  for(int i=0;i<16;i++){ int idx=i0+i; if(idx<N) s+=deg[idx]; }
  sh[t]=s; __syncthreads();
  for(int off=128; off>0; off>>=1){ if(t<off) sh[t]+=sh[t+off]; __syncthreads(); }
  if(t==0) bsum[b]=sh[0];
}

// phase 2: single small block exclusive-scans the block sums (nb <= 1024)
__global__ void k_scan2(int* __restrict__ bsum, int nb){
  __shared__ int sh[1024];
  int t = threadIdx.x;
  int v = (t<nb)? bsum[t] : 0;
  sh[t]=v; __syncthreads();
  for(int off=1; off<1024; off<<=1){
    int u = (t>=off)? sh[t-off] : 0;
    __syncthreads();
    sh[t]+=u;
    __syncthreads();
  }
  if(t<nb) bsum[t] = sh[t]-v;   // exclusive prefix of block sums
}

// phase 3: re-read tile, block-local exclusive scan + block offset, write rowptr/cursor
__global__ __launch_bounds__(256) void k_scan3(const int* __restrict__ deg, int N, int E,
                                               const int* __restrict__ bsum,
                                               int* __restrict__ rowptr, int* __restrict__ cursor){
  __shared__ int sh[256];
  int b = blockIdx.x, t = threadIdx.x;
  int i0 = b*SCAN_TILE + t*16;
  int local[16];
  int s = 0;
  #pragma unroll
  for(int i=0;i<16;i++){
    int idx=i0+i;
    int d = (idx<N)? deg[idx] : 0;
    local[i]=d; s+=d;
  }
  sh[t]=s; __syncthreads();
  for(int off=1; off<256; off<<=1){
    int u = (t>=off)? sh[t-off] : 0;
    __syncthreads();
    sh[t]+=u;
    __syncthreads();
  }
  int run = bsum[b] + sh[t]-s;
  #pragma unroll
  for(int i=0;i<16;i++){
    int idx=i0+i;
    if(idx<N){ rowptr[idx]=run; cursor[idx]=run; run+=local[i]; }
  }
  if(b==0 && t==0) rowptr[N]=E;
}

__global__ void k_fill(const int* __restrict__ ei, const float* __restrict__ ea, int E,
                       int* __restrict__ cursor, int* __restrict__ srcs,
                       unsigned short* __restrict__ ewb){
  int e = blockIdx.x*256 + threadIdx.x;
  if(e<E){
    int d = ei[E+e];
    int p = atomicAdd(&cursor[d], 1);
    srcs[p] = ei[e];
    ewb[p]  = f2b(ea[e]);
  }
}

// ---------------- weight f32 -> bf16 prep (8 arrays packed into wbf) ----------------
__global__ void k_prep_w(const float* __restrict__ a0, const float* __restrict__ a1,
                         const float* __restrict__ a2, const float* __restrict__ a3,
                         const float* __restrict__ a4, const float* __restrict__ a5,
                         const float* __restrict__ a6, const float* __restrict__ a7,
                         unsigned short* __restrict__ out){
  int i = blockIdx.x*256 + threadIdx.x;
  const float* src; int off;
  if      (i< 4096){ src=a0; off=0;     }
  else if (i< 8192){ src=a1; off=4096;  }
  else if (i<12288){ src=a2; off=8192;  }
  else if (i<16384){ src=a3; off=12288; }
  else if (i<40960){ src=a4; off=16384; }
  else if (i<53248){ src=a5; off=40960; }
  else if (i<65536){ src=a6; off=53248; }
  else if (i<77824){ src=a7; off=65536; }
  else return;
  out[i] = f2b(src[i-off]);
}

// ---------------- mean aggregation (wave per node, lane = feature, 4-deep gather) ----------------
__global__ void k_aggregate(const float* __restrict__ xin, int ldx,
                            const int* __restrict__ rowptr,
                            const int* __restrict__ srcs, const unsigned short* __restrict__ ewb,
                            int N, unsigned short* __restrict__ aggb){
  int node = blockIdx.x*4 + (threadIdx.x>>6);
  int lane = threadIdx.x & 63;
  if(node>=N) return;
  int b = rowptr[node], e = rowptr[node+1];
  float acc = 0.f;
  int i = b;
  for(; i+4<=e; i+=4){
    int s0=srcs[i], s1=srcs[i+1], s2=srcs[i+2], s3=srcs[i+3];
    float w0=b2f(ewb[i]),  w1=b2f(ewb[i+1]), w2=b2f(ewb[i+2]), w3=b2f(ewb[i+3]);
    float v0=xin[(size_t)s0*ldx+lane], v1=xin[(size_t)s1*ldx+lane];
    float v2=xin[(size_t)s2*ldx+lane], v3=xin[(size_t)s3*ldx+lane];
    acc = fmaf(v0,w0,acc); acc = fmaf(v1,w1,acc);
    acc = fmaf(v2,w2,acc); acc = fmaf(v3,w3,acc);
  }
  for(; i<e; i++)
    acc = fmaf(xin[(size_t)srcs[i]*ldx+lane], b2f(ewb[i]), acc);
  acc *= 1.f/(float)max(e-b, 1);
  aggb[(size_t)node*64 + lane] = f2b(acc);
}

// ---------------- SAGE MFMA: s = agg@lW^T + x@rW^T + lb ; per-feature stats ----------------
__global__ __launch_bounds__(256) void k_sage_mfma(
    const unsigned short* __restrict__ aggb,   // [N][64] bf16
    const float* __restrict__ xin, int ldx,    // [N][ldx] f32, cols 0..63
    const unsigned short* __restrict__ lWb,    // [64][64] bf16 (torch [out][in])
    const unsigned short* __restrict__ rWb,    // [64][64] bf16
    const float* __restrict__ lb,
    int N, float* __restrict__ sbuf,
    float* __restrict__ gsum, float* __restrict__ gsq){
  __shared__ float red[2][4][64];
  int tid = threadIdx.x;
  int wid = tid>>6, lane = tid&63;
  int l15 = lane&15, lk = lane>>4;
  int m0 = blockIdx.x*64 + wid*16;
  int arow = min(m0 + l15, N-1);
  f32x4 acc[4];
  #pragma unroll
  for(int c=0;c<4;c++) acc[c] = (f32x4){0.f,0.f,0.f,0.f};

  #pragma unroll
  for(int kt=0; kt<2; kt++){                    // agg @ lW^T (K=64)
    s16x8 a = ld8(&aggb[(size_t)arow*64 + kt*32 + lk*8]);
    #pragma unroll
    for(int c=0;c<4;c++){
      s16x8 b = ld8(&lWb[(size_t)(c*16+l15)*64 + kt*32 + lk*8]);
      acc[c] = MFMA16(a,b,acc[c]);
    }
  }
  #pragma unroll
  for(int kt=0; kt<2; kt++){                    // x @ rW^T (K=64)
    s16x8 a = cvt8(&xin[(size_t)arow*ldx + kt*32 + lk*8]);
    #pragma unroll
    for(int c=0;c<4;c++){
      s16x8 b = ld8(&rWb[(size_t)(c*16+l15)*64 + kt*32 + lk*8]);
      acc[c] = MFMA16(a,b,acc[c]);
    }
  }
  // epilogue: bias, store s, per-feature sum/sumsq
  float ssum[4], ssq[4];
  #pragma unroll
  for(int c=0;c<4;c++){
    int col = c*16 + l15;
    float bias = lb[col];
    float s_=0.f, q_=0.f;
    #pragma unroll
    for(int r=0;r<4;r++){
      int row = m0 + lk*4 + r;
      if(row<N){
        float v = acc[c][r] + bias;
        sbuf[(size_t)row*64 + col] = v;
        s_ += v; q_ += v*v;
      }
    }
    ssum[c]=s_; ssq[c]=q_;
  }
  #pragma unroll
  for(int c=0;c<4;c++){
    ssum[c] += __shfl_xor(ssum[c],16); ssum[c] += __shfl_xor(ssum[c],32);
    ssq[c]  += __shfl_xor(ssq[c],16);  ssq[c]  += __shfl_xor(ssq[c],32);
  }
  if(lk==0){
    #pragma unroll
    for(int c=0;c<4;c++){
      red[0][wid][c*16+l15] = ssum[c];
      red[1][wid][c*16+l15] = ssq[c];
    }
  }
  __syncthreads();
  if(tid<64){
    float a = red[0][0][tid]+red[0][1][tid]+red[0][2][tid]+red[0][3][tid];
    float b = red[1][0][tid]+red[1][1][tid]+red[1][2][tid]+red[1][3][tid];
    atomicAdd(&gsum[tid], a);
    atomicAdd(&gsq[tid],  b);
  }
}

// ---------------- GraphNorm finalize ----------------
__global__ void k_norm_fin(const float* __restrict__ gsum, const float* __restrict__ gsq,
                           const float* __restrict__ w, const float* __restrict__ b,
                           const float* __restrict__ ms,
                           float Ninv, float* __restrict__ alpha, float* __restrict__ beta){
  int j = threadIdx.x;
  float m   = gsum[j]*Ninv;
  float ex2 = gsq[j]*Ninv;
  float msv = ms[j];
  float var = ex2 - m*m*msv*(2.f-msv);   // E[(s-ms*m)^2]
  float rinv = rsqrtf(var + 1e-5f);
  float a = w[j]*rinv;
  alpha[j] = a;
  beta[j]  = b[j] - a*msv*m;
}

// ---------------- y = relu(alpha*s + beta) -> xc slab (row stride 128) ----------------
__global__ void k_apply(const float* __restrict__ sbuf, const float* __restrict__ ab,
                        int N, float* __restrict__ outbase){
  int t = blockIdx.x*256 + threadIdx.x;
  int total = N*16;
  if(t>=total) return;
  int node = t>>4, q = t&15;
  float4 s  = *reinterpret_cast<const float4*>(&sbuf[(size_t)node*64 + q*4]);
  float4 al = *reinterpret_cast<const float4*>(&ab[q*4]);
  float4 be = *reinterpret_cast<const float4*>(&ab[64 + q*4]);
  float4 o;
  o.x = fmaxf(fmaf(s.x,al.x,be.x), 0.f);
  o.y = fmaxf(fmaf(s.y,al.y,be.y), 0.f);
  o.z = fmaxf(fmaf(s.z,al.z,be.z), 0.f);
  o.w = fmaxf(fmaf(s.w,al.w,be.w), 0.f);
  *reinterpret_cast<float4*>(&outbase[(size_t)node*128 + q*4]) = o;
}

// ---------------- fused GRU via MFMA ----------------
__global__ __launch_bounds__(256) void k_gru_mfma(
    const float* __restrict__ xin, int ldx, int K1, // gi input [N][ldx] f32
    const float* __restrict__ hin,                  // [N][64] f32 (gh input + h_prev)
    const unsigned short* __restrict__ wihb,        // [192][K1] bf16
    const unsigned short* __restrict__ whhb,        // [192][64] bf16
    const float* __restrict__ bih, const float* __restrict__ bhh,
    int N, float* __restrict__ hout){
  int tid = threadIdx.x;
  int wid = tid>>6, lane = tid&63;
  int l15 = lane&15, lk = lane>>4;
  int m0 = blockIdx.x*16;
  int c0 = wid*16;
  int arow = min(m0 + l15, N-1);
  f32x4 ai[3], ah[3];
  #pragma unroll
  for(int g=0;g<3;g++){ ai[g]=(f32x4){0.f,0.f,0.f,0.f}; ah[g]=(f32x4){0.f,0.f,0.f,0.f}; }

  for(int kt=0; kt<K1/32; kt++){                // gi: xin @ wih^T
    s16x8 a = cvt8(&xin[(size_t)arow*ldx + kt*32 + lk*8]);
    #pragma unroll
    for(int g=0; g<3; g++){
      s16x8 b = ld8(&wihb[(size_t)(g*64 + c0 + l15)*K1 + kt*32 + lk*8]);
      ai[g] = MFMA16(a,b,ai[g]);
    }
  }
  #pragma unroll
  for(int kt=0; kt<2; kt++){                    // gh: hin @ whh^T (K=64)
    s16x8 a = cvt8(&hin[(size_t)arow*64 + kt*32 + lk*8]);
    #pragma unroll
    for(int g=0; g<3; g++){
      s16x8 b = ld8(&whhb[(size_t)(g*64 + c0 + l15)*64 + kt*32 + lk*8]);
      ah[g] = MFMA16(a,b,ah[g]);
    }
  }
  int j = c0 + l15;
  float bi_r=bih[j], bi_z=bih[64+j], bi_n=bih[128+j];
  float bh_r=bhh[j], bh_z=bhh[64+j], bh_n=bhh[128+j];
  #pragma unroll
  for(int r=0;r<4;r++){
    int row = m0 + lk*4 + r;
    if(row<N){
      float hp = hin[(size_t)row*64 + j];
      float rg = sigf(ai[0][r]+bi_r + ah[0][r]+bh_r);
      float z  = sigf(ai[1][r]+bi_z + ah[1][r]+bh_z);
      float n  = tanhf_(fmaf(rg, ah[2][r]+bh_n, ai[2][r]+bi_n));
      hout[(size_t)row*64 + j] = fmaf(z, hp-n, n);
    }
  }
}

extern "C" void kernel_launch(void* const* d_in, const int* in_sizes, int n_in,
                              void* d_out, int out_size, void* d_ws, size_t ws_size,
                              hipStream_t stream) {
  const float* x    = (const float*)d_in[0];
  const int*   ei   = (const int*)d_in[1];
  const float* ea   = (const float*)d_in[2];
  const float* h1   = (const float*)d_in[3];
  const float* h2   = (const float*)d_in[4];
  const float* s1lW = (const float*)d_in[5];
  const float* s1lb = (const float*)d_in[6];
  const float* s1rW = (const float*)d_in[7];
  const float* s2lW = (const float*)d_in[8];
  const float* s2lb = (const float*)d_in[9];
  const float* s2rW = (const float*)d_in[10];
  const float* gn1w = (const float*)d_in[11];
  const float* gn1b = (const float*)d_in[12];
  const float* gn1ms= (const float*)d_in[13];
  const float* gn2w = (const float*)d_in[14];
  const float* gn2b = (const float*)d_in[15];
  const float* gn2ms= (const float*)d_in[16];
  const float* g1wih= (const float*)d_in[17];
  const float* g1whh= (const float*)d_in[18];
  const float* g1bih= (const float*)d_in[19];
  const float* g1bhh= (const float*)d_in[20];
  const float* g2wih= (const float*)d_in[21];
  const float* g2whh= (const float*)d_in[22];
  const float* g2bih= (const float*)d_in[23];
  const float* g2bhh= (const float*)d_in[24];

  int N = in_sizes[0]/64;
  int E = in_sizes[2];
  if(N<=0) return;

  // ---- workspace layout (bytes) ----
  char* base = (char*)d_ws;
  size_t off = 0;
  float* gsum1 = (float*)(base);      // 512 f32: stats + ab
  float* gsq1  = gsum1 + 64;
  float* gsum2 = gsum1 + 128;
  float* gsq2  = gsum1 + 192;
  float* ab1   = gsum1 + 256;
  float* ab2   = gsum1 + 384;
  off = 512*4;
  int nb_scan = (N + SCAN_TILE-1)/SCAN_TILE;     // 25 for N=100k (<=1024 required)
  int* bsum   = (int*)(base+off); off += 1024*4;
  int* deg    = (int*)(base+off); off += (size_t)N*4;
  int* rowptr = (int*)(base+off); off += ((size_t)N+1)*4;
  int* cursor = (int*)(base+off); off += (size_t)N*4;
  int* srcs   = (int*)(base+off); off += (size_t)E*4;
  unsigned short* ewb = (unsigned short*)(base+off); off += (size_t)E*2;
  off = (off + 63) & ~(size_t)63;
  unsigned short* wbf = (unsigned short*)(base+off);
  unsigned short* s1lWb = wbf;
  unsigned short* s1rWb = wbf + 4096;
  unsigned short* s2lWb = wbf + 8192;
  unsigned short* s2rWb = wbf + 12288;
  unsigned short* g1wihb= wbf + 16384;   // 24576
  unsigned short* g1whhb= wbf + 40960;   // 12288
  unsigned short* g2wihb= wbf + 53248;   // 12288
  unsigned short* g2whhb= wbf + 65536;   // 12288  (total 77824)

  // ---- d_out regions ----
  float* xc  = (float*)d_out;                  // [N][128]
  float* h1n = xc + (size_t)N*128;             // [N][64]
  float* h2n = h1n + (size_t)N*64;             // [N][64]
  float* sbuf = h1n;                           // raw SAGE out, dead before GRU1 writes h1n
  unsigned short* aggb = (unsigned short*)h2n; // [N][64] bf16, dead before GRU2 writes h2n

  hipMemsetAsync(gsum1, 0, 512*4, stream);
  hipMemsetAsync(deg, 0, (size_t)N*4, stream);

  int eb  = (E+255)/256;
  k_count<<<eb,256,0,stream>>>(ei, E, deg);
  k_scan1<<<nb_scan,256,0,stream>>>(deg, N, bsum);
  k_scan2<<<1,1024,0,stream>>>(bsum, nb_scan);
  k_scan3<<<nb_scan,256,0,stream>>>(deg, N, E, bsum, rowptr, cursor);
  k_fill <<<eb,256,0,stream>>>(ei, ea, E, cursor, srcs, ewb);
  k_prep_w<<<(77824+255)/256,256,0,stream>>>(s1lW,s1rW,s2lW,s2rW,g1wih,g1whh,g2wih,g2whh, wbf);

  int nb4 = (N+3)/4;
  int gb  = (N+63)/64;
  int apb = (N*16+255)/256;
  int grb = (N+15)/16;

  // layer 1
  k_aggregate<<<nb4,256,0,stream>>>(x, 64, rowptr, srcs, ewb, N, aggb);
  k_sage_mfma<<<gb,256,0,stream>>>(aggb, x, 64, s1lWb, s1rWb, s1lb, N, sbuf, gsum1, gsq1);
  k_norm_fin<<<1,64,0,stream>>>(gsum1, gsq1, gn1w, gn1b, gn1ms, 1.f/(float)N, ab1, ab1+64);
  k_apply<<<apb,256,0,stream>>>(sbuf, ab1, N, xc);          // x1 -> cols 0..63

  // layer 2 (x1 read from xc, stride 128)
  k_aggregate<<<nb4,256,0,stream>>>(xc, 128, rowptr, srcs, ewb, N, aggb);
  k_sage_mfma<<<gb,256,0,stream>>>(aggb, xc, 128, s2lWb, s2rWb, s2lb, N, sbuf, gsum2, gsq2);
  k_norm_fin<<<1,64,0,stream>>>(gsum2, gsq2, gn2w, gn2b, gn2ms, 1.f/(float)N, ab2, ab2+64);
  k_apply<<<apb,256,0,stream>>>(sbuf, ab2, N, xc + 64);     // x2 -> cols 64..127

  // GRUs (MFMA, fused gates) — overwrite scratch regions with real h1n/h2n
  k_gru_mfma<<<grb,256,0,stream>>>(xc, 128, 128, h1, g1wihb, g1whhb, g1bih, g1bhh, N, h1n);
  k_gru_mfma<<<grb,256,0,stream>>>(h1n, 64, 64,  h2, g2wihb, g2whhb, g2bih, g2bhh, N, h2n);
}